// Round 1
// baseline (195.188 us; speedup 1.0000x reference)
//
#include <hip/hip_runtime.h>

#define BB 4
#define TT 1024
#define CC 1024
#define HH 16
#define KSZ 31
#define PADL 15
#define RR 64
#define NLOG (HH * KSZ)   // 496
#define MROWS (BB * TT)   // 4096
#define CONV_TT 64        // t-tile per conv block

// ---------------------------------------------------------------------------
// Kernel 1: logits GEMM.  L[m][n] = sum_c X[m][c] * W[n][c]
// M=4096, N=496 (padded to 512 in tiling), K=1024. fp32, register-tiled.
// Block: 256 threads computes a 64x64 output tile with BK=32.
// ---------------------------------------------------------------------------
__global__ __launch_bounds__(256) void gemm_logits(const float* __restrict__ X,
                                                   const float* __restrict__ W,
                                                   float* __restrict__ L) {
    __shared__ float As[64][33];   // +1 pad: conflict-free column reads
    __shared__ float Bs[64][33];

    const int tid = threadIdx.x;
    const int m0 = blockIdx.y * 64;
    const int n0 = blockIdx.x * 64;
    const int lr = tid >> 3;          // 0..31  (row within half-tile)
    const int lc = (tid & 7) * 4;     // 0,4,...,28 (col, float4)
    const int ty = tid >> 4;          // 0..15 -> m sub-block
    const int tx = tid & 15;          // 0..15 -> n sub-block

    float acc[4][4] = {};

    for (int k0 = 0; k0 < CC; k0 += 32) {
#pragma unroll
        for (int half = 0; half < 2; ++half) {
            const int r = lr + half * 32;
            // A tile: rows m0+r, always valid (M=4096 divides by 64)
            float4 av = *reinterpret_cast<const float4*>(
                &X[(size_t)(m0 + r) * CC + k0 + lc]);
            As[r][lc + 0] = av.x; As[r][lc + 1] = av.y;
            As[r][lc + 2] = av.z; As[r][lc + 3] = av.w;
            // B tile: rows n0+r, guard n < 496
            const int n = n0 + r;
            float4 bv = make_float4(0.f, 0.f, 0.f, 0.f);
            if (n < NLOG)
                bv = *reinterpret_cast<const float4*>(
                    &W[(size_t)n * CC + k0 + lc]);
            Bs[r][lc + 0] = bv.x; Bs[r][lc + 1] = bv.y;
            Bs[r][lc + 2] = bv.z; Bs[r][lc + 3] = bv.w;
        }
        __syncthreads();
#pragma unroll
        for (int kk = 0; kk < 32; ++kk) {
            float a[4], b[4];
#pragma unroll
            for (int i = 0; i < 4; ++i) a[i] = As[ty * 4 + i][kk];
#pragma unroll
            for (int j = 0; j < 4; ++j) b[j] = Bs[tx * 4 + j][kk];
#pragma unroll
            for (int i = 0; i < 4; ++i)
#pragma unroll
                for (int j = 0; j < 4; ++j)
                    acc[i][j] = fmaf(a[i], b[j], acc[i][j]);
        }
        __syncthreads();
    }

#pragma unroll
    for (int i = 0; i < 4; ++i) {
        const int m = m0 + ty * 4 + i;
#pragma unroll
        for (int j = 0; j < 4; ++j) {
            const int n = n0 + tx * 4 + j;
            if (n < NLOG) L[(size_t)m * NLOG + n] = acc[i][j];
        }
    }
}

// ---------------------------------------------------------------------------
// Kernel 2: fused softmax(K=31) + depthwise band conv.
// Block = (b, h, 64-t tile), 256 threads = 4 waves.
// out[b,t,h,r] = sum_k softmax(L)[b,t,h,k] * x[b, t+k-15, h, r]
// ---------------------------------------------------------------------------
__global__ __launch_bounds__(256) void conv_softmax(const float* __restrict__ X,
                                                    const float* __restrict__ L,
                                                    float* __restrict__ out) {
    __shared__ float xs[CONV_TT + KSZ - 1][RR];  // 94 x 64 f32 = 24 KB
    __shared__ float ws[CONV_TT][KSZ + 1];       // 64 x 32 f32 =  8 KB

    const int tid = threadIdx.x;
    int bid = blockIdx.x;
    const int tt = bid & 15; bid >>= 4;   // T/64 = 16 tiles
    const int h  = bid & 15; bid >>= 4;   // H = 16
    const int b  = bid;                   // B = 4
    const int t0 = tt * CONV_TT;

    // stage x halo tile: rows t0-15 .. t0+78 (zero outside [0,T))
    for (int idx = tid; idx < (CONV_TT + KSZ - 1) * RR; idx += 256) {
        const int row = idx >> 6;
        const int col = idx & 63;
        const int tg = t0 - PADL + row;
        float v = 0.f;
        if (tg >= 0 && tg < TT)
            v = X[((size_t)(b * TT + tg)) * CC + h * RR + col];
        xs[row][col] = v;
    }

    // softmax: one thread per t-row (threads 0..63)
    if (tid < CONV_TT) {
        const int tg = t0 + tid;
        const float* lp = &L[((size_t)(b * TT + tg)) * NLOG + h * KSZ];
        float lv[KSZ];
        float mx = -1e30f;
#pragma unroll
        for (int k = 0; k < KSZ; ++k) { lv[k] = lp[k]; mx = fmaxf(mx, lv[k]); }
        float s = 0.f;
#pragma unroll
        for (int k = 0; k < KSZ; ++k) { lv[k] = __expf(lv[k] - mx); s += lv[k]; }
        const float inv = 1.f / s;
#pragma unroll
        for (int k = 0; k < KSZ; ++k) ws[tid][k] = lv[k] * inv;
    }
    __syncthreads();

    const int lane = tid & 63;   // r
    const int wv = tid >> 6;     // wave 0..3, each owns 16 t's
#pragma unroll
    for (int i = 0; i < CONV_TT / 4; ++i) {
        const int tl = wv * (CONV_TT / 4) + i;
        float acc = 0.f;
#pragma unroll
        for (int k = 0; k < KSZ; ++k)
            acc = fmaf(ws[tl][k], xs[tl + k][lane], acc);  // ws: wave-broadcast
        out[((size_t)(b * TT + t0 + tl)) * CC + h * RR + lane] = acc;
    }
}

// ---------------------------------------------------------------------------
extern "C" void kernel_launch(void* const* d_in, const int* in_sizes, int n_in,
                              void* d_out, int out_size, void* d_ws, size_t ws_size,
                              hipStream_t stream) {
    const float* x = (const float*)d_in[0];
    const float* W = (const float*)d_in[1];
    float* out = (float*)d_out;
    float* Lbuf = (float*)d_ws;   // 4096 * 496 f32 = 8.1 MB scratch

    dim3 g1(8, 64);               // N tiles x M tiles
    gemm_logits<<<g1, 256, 0, stream>>>(x, W, Lbuf);

    conv_softmax<<<BB * HH * (TT / CONV_TT), 256, 0, stream>>>(x, Lbuf, out);
}

// Round 2
// 115.516 us; speedup vs baseline: 1.6897x; 1.6897x over previous
//
#include <hip/hip_runtime.h>
#include <stdint.h>

typedef __attribute__((ext_vector_type(4))) float f32x4;
typedef __attribute__((ext_vector_type(8))) short short8;
typedef __attribute__((ext_vector_type(4))) unsigned short u16x4;

#define BB 4
#define TT 1024
#define CC 1024
#define HH 16
#define KSZ 31
#define PADL 15
#define RR 64
#define NL 496      // H*K
#define NP 512      // padded N for GEMM
#define MM 4096     // B*T

// round-to-nearest-even f32 -> bf16
__device__ __forceinline__ unsigned short f2bf(float f) {
    uint32_t u = __float_as_uint(f);
    u += 0x7FFFu + ((u >> 16) & 1u);
    return (unsigned short)(u >> 16);
}

__device__ __forceinline__ void gload_lds16(const void* g, void* l) {
    __builtin_amdgcn_global_load_lds(
        (const __attribute__((address_space(1))) unsigned int*)g,
        (__attribute__((address_space(3))) unsigned int*)l, 16, 0, 0);
}

// ---------------------------------------------------------------------------
// Kernel 1: cast X -> Xb (bf16), W -> Wb (bf16, zero-padded to 512 rows)
// ---------------------------------------------------------------------------
__global__ __launch_bounds__(256) void cast_kernel(const float* __restrict__ X,
                                                   const float* __restrict__ W,
                                                   unsigned short* __restrict__ Xb,
                                                   unsigned short* __restrict__ Wb) {
    const int i = blockIdx.x * 256 + threadIdx.x;
    const int nx4 = MM * CC / 4;   // 1,048,576
    const int nw4 = NP * CC / 4;   // 131,072
    if (i < nx4) {
        f32x4 v = ((const f32x4*)X)[i];
        u16x4 o = { f2bf(v[0]), f2bf(v[1]), f2bf(v[2]), f2bf(v[3]) };
        ((u16x4*)Xb)[i] = o;
    } else if (i < nx4 + nw4) {
        const int j = i - nx4;
        const int n = j >> 8;      // W-row = j*4/1024
        u16x4 o = { 0, 0, 0, 0 };
        if (n < NL) {
            f32x4 v = ((const f32x4*)W)[j];
            o[0] = f2bf(v[0]); o[1] = f2bf(v[1]); o[2] = f2bf(v[2]); o[3] = f2bf(v[3]);
        }
        ((u16x4*)Wb)[j] = o;
    }
}

// ---------------------------------------------------------------------------
// Kernel 2: bf16 MFMA GEMM.  L[m][n] = sum_c Xb[m][c] * Wb[n][c]
// 64x64 tile, BK=64, 4 waves (each 32x32 out), global_load_lds + XOR swizzle.
// LDS layout: row-major [64 rows][64 bf16], 16B chunk kc swizzled: kc ^= (row&7)
// ---------------------------------------------------------------------------
__global__ __launch_bounds__(256) void gemm_mfma(const unsigned short* __restrict__ Xb,
                                                 const unsigned short* __restrict__ Wb,
                                                 float* __restrict__ L) {
    __shared__ unsigned short As[64 * 64];   // 8 KB
    __shared__ unsigned short Bs[64 * 64];   // 8 KB

    const int tid = threadIdx.x;
    const int lane = tid & 63;
    const int wv = tid >> 6;
    const int wm = wv >> 1, wn = wv & 1;           // 2x2 wave grid
    const int m0 = blockIdx.y * 64, n0 = blockIdx.x * 64;

    f32x4 acc[2][2] = {};

    for (int kt = 0; kt < CC / 64; ++kt) {
        const int k0 = kt * 64;
#pragma unroll
        for (int p = 0; p < 2; ++p) {
            const int c = p * 256 + tid;           // chunk 0..511
            const int row = c >> 3, kcs = c & 7;   // lds holds global kc = kcs ^ (row&7)
            const int kg = (kcs ^ (row & 7)) << 3; // element offset within BK
            gload_lds16(Xb + (size_t)(m0 + row) * CC + k0 + kg, (char*)As + c * 16);
            gload_lds16(Wb + (size_t)(n0 + row) * CC + k0 + kg, (char*)Bs + c * 16);
        }
        __syncthreads();
#pragma unroll
        for (int ks = 0; ks < 2; ++ks) {
            short8 af[2], bfv[2];
            const int kc = ks * 4 + (lane >> 4);
#pragma unroll
            for (int s = 0; s < 2; ++s) {
                const int ra = wm * 32 + s * 16 + (lane & 15);
                af[s] = *(const short8*)((const char*)As + ra * 128 + ((kc ^ (ra & 7)) << 4));
                const int rb = wn * 32 + s * 16 + (lane & 15);
                bfv[s] = *(const short8*)((const char*)Bs + rb * 128 + ((kc ^ (rb & 7)) << 4));
            }
#pragma unroll
            for (int si = 0; si < 2; ++si)
#pragma unroll
                for (int sj = 0; sj < 2; ++sj)
                    acc[si][sj] = __builtin_amdgcn_mfma_f32_16x16x32_bf16(
                        af[si], bfv[sj], acc[si][sj], 0, 0, 0);
        }
        __syncthreads();
    }

    // epilogue: C/D layout col=lane&15, row=(lane>>4)*4+reg  [m89]
    const int col = lane & 15, rbase = (lane >> 4) * 4;
#pragma unroll
    for (int si = 0; si < 2; ++si)
#pragma unroll
        for (int sj = 0; sj < 2; ++sj) {
            const int n = n0 + wn * 32 + sj * 16 + col;
            if (n < NL) {
#pragma unroll
                for (int r = 0; r < 4; ++r) {
                    const int m = m0 + wm * 32 + si * 16 + rbase + r;
                    L[(size_t)m * NL + n] = acc[si][sj][r];
                }
            }
        }
}

// ---------------------------------------------------------------------------
// Kernel 3: softmax over K=31, store NORMALIZED weights padded to 32 (w[31]=0)
// one thread per (m,h); wq layout [m][h][32]
// ---------------------------------------------------------------------------
__global__ __launch_bounds__(256) void softmax_kernel(const float* __restrict__ L,
                                                      float* __restrict__ wq) {
    const int g = blockIdx.x * 256 + threadIdx.x;   // 0..65535
    const int m = g >> 4, h = g & 15;
    const float* lp = L + (size_t)m * NL + h * KSZ;
    float lv[KSZ];
    float mx = -1e30f;
#pragma unroll
    for (int k = 0; k < KSZ; ++k) { lv[k] = lp[k]; mx = fmaxf(mx, lv[k]); }
    float s = 0.f;
#pragma unroll
    for (int k = 0; k < KSZ; ++k) { lv[k] = __expf(lv[k] - mx); s += lv[k]; }
    const float inv = 1.f / s;
    f32x4* op = (f32x4*)(wq + (size_t)g * 32);
#pragma unroll
    for (int q = 0; q < 8; ++q) {
        f32x4 o;
#pragma unroll
        for (int j = 0; j < 4; ++j) {
            const int k = q * 4 + j;
            o[j] = (k < KSZ) ? lv[k] * inv : 0.f;
        }
        op[q] = o;
    }
}

// ---------------------------------------------------------------------------
// Kernel 4: depthwise band conv.  Block = (b, h, 64-t tile), 4 waves x 16 t.
// x staged TRANSPOSED in LDS: xsT[r=lane][t-col], stride 96 floats, 16B-chunk
// XOR swizzle (tc ^= lane&7) -> ds_read_b128 along t, ~optimal bank behavior.
// Weights read as uniform global float4 (L2-resident, normalized already).
// ---------------------------------------------------------------------------
__global__ __launch_bounds__(256) void conv_kernel(const float* __restrict__ X,
                                                   const float* __restrict__ wq,
                                                   float* __restrict__ out) {
    __shared__ float xsT[64 * 96];   // 24 KB

    const int tid = threadIdx.x, lane = tid & 63, wv = tid >> 6;
    int bid = blockIdx.x;
    const int tt = bid & 15;
    const int h = (bid >> 4) & 15;
    const int b = bid >> 8;
    const int t0 = tt * 64;

    // stage + transpose 96 t-rows (rows 94/95 zeroed; OOB t zeroed)
    for (int i = 0; i < 24; ++i) {
        const int row = i * 4 + wv;          // t-col 0..95
        const int tg = t0 - PADL + row;
        float v = 0.f;
        if (row < 94 && tg >= 0 && tg < TT)
            v = X[(size_t)(b * TT + tg) * CC + h * RR + lane];
        const int tc = row >> 2;
        *(float*)((char*)xsT + lane * 384 + ((tc ^ (lane & 7)) << 4) + (row & 3) * 4) = v;
    }
    __syncthreads();

#pragma unroll
    for (int g = 0; g < 2; ++g) {
        const int gl = wv * 16 + g * 8;      // group base t (local), multiple of 8
        // 40-float x window: chunks gl/4 .. gl/4+9
        f32x4 xw[10];
#pragma unroll
        for (int q = 0; q < 10; ++q) {
            const int tc = (gl >> 2) + q;
            xw[q] = *(const f32x4*)((const char*)xsT + lane * 384 + ((tc ^ (lane & 7)) << 4));
        }
        float acc[8] = {};
#pragma unroll
        for (int tl = 0; tl < 8; ++tl) {
            const f32x4* wp = (const f32x4*)(wq +
                (size_t)((b * TT + t0 + gl + tl) * HH + h) * 32);
#pragma unroll
            for (int kq = 0; kq < 8; ++kq) {
                const f32x4 w4 = wp[kq];
#pragma unroll
                for (int j = 0; j < 4; ++j) {
                    const int e = tl + kq * 4 + j;     // window index, static
                    acc[tl] = fmaf(w4[j], xw[e >> 2][e & 3], acc[tl]);
                }
            }
        }
#pragma unroll
        for (int tl = 0; tl < 8; ++tl)
            out[(size_t)(b * TT + t0 + gl + tl) * CC + h * RR + lane] = acc[tl];
    }
}

// ---------------------------------------------------------------------------
extern "C" void kernel_launch(void* const* d_in, const int* in_sizes, int n_in,
                              void* d_out, int out_size, void* d_ws, size_t ws_size,
                              hipStream_t stream) {
    const float* x = (const float*)d_in[0];
    const float* W = (const float*)d_in[1];
    float* out = (float*)d_out;
    char* ws = (char*)d_ws;

    unsigned short* Xb = (unsigned short*)ws;                       // 8,388,608 B
    unsigned short* Wb = (unsigned short*)(ws + (size_t)MM * CC * 2); // 1,048,576 B
    float* L = (float*)d_out;   // 8.1 MB scratch inside d_out (dead before conv)
    float* wq = (float*)ws;     // reuses Xb region after gemm (Xb dead)

    cast_kernel<<<(MM * CC / 4 + NP * CC / 4 + 255) / 256, 256, 0, stream>>>(x, W, Xb, Wb);
    gemm_mfma<<<dim3(NP / 64, MM / 64), 256, 0, stream>>>(Xb, Wb, L);
    softmax_kernel<<<MM * HH / 256, 256, 0, stream>>>(L, wq);
    conv_kernel<<<BB * HH * (TT / 64), 256, 0, stream>>>(x, wq, out);
}

// Round 4
// 111.911 us; speedup vs baseline: 1.7441x; 1.0322x over previous
//
#include <hip/hip_runtime.h>
#include <stdint.h>

typedef __attribute__((ext_vector_type(4))) float f32x4;
typedef __attribute__((ext_vector_type(8))) short short8;
typedef __attribute__((ext_vector_type(4))) unsigned short u16x4;

#define BB 4
#define TT 1024
#define CC 1024
#define HH 16
#define KSZ 31
#define PADL 15
#define RR 64
#define NL 496      // H*K
#define NP 512      // padded N for GEMM
#define MM 4096     // B*T

// round-to-nearest-even f32 -> bf16
__device__ __forceinline__ unsigned short f2bf(float f) {
    uint32_t u = __float_as_uint(f);
    u += 0x7FFFu + ((u >> 16) & 1u);
    return (unsigned short)(u >> 16);
}

__device__ __forceinline__ void gload_lds16(const void* g, void* l) {
    __builtin_amdgcn_global_load_lds(
        (const __attribute__((address_space(1))) unsigned int*)g,
        (__attribute__((address_space(3))) unsigned int*)l, 16, 0, 0);
}

// ---------------------------------------------------------------------------
// Kernel 1: cast X -> Xb (bf16), W -> Wb (bf16, zero-padded to 512 rows)
// ---------------------------------------------------------------------------
__global__ __launch_bounds__(256) void cast_kernel(const float* __restrict__ X,
                                                   const float* __restrict__ W,
                                                   unsigned short* __restrict__ Xb,
                                                   unsigned short* __restrict__ Wb) {
    const int i = blockIdx.x * 256 + threadIdx.x;
    const int nx4 = MM * CC / 4;   // 1,048,576
    const int nw4 = NP * CC / 4;   // 131,072
    if (i < nx4) {
        f32x4 v = ((const f32x4*)X)[i];
        u16x4 o = { f2bf(v[0]), f2bf(v[1]), f2bf(v[2]), f2bf(v[3]) };
        ((u16x4*)Xb)[i] = o;
    } else if (i < nx4 + nw4) {
        const int j = i - nx4;
        const int n = j >> 8;      // W-row = j*4/1024
        u16x4 o = { 0, 0, 0, 0 };
        if (n < NL) {
            f32x4 v = ((const f32x4*)W)[j];
            o[0] = f2bf(v[0]); o[1] = f2bf(v[1]); o[2] = f2bf(v[2]); o[3] = f2bf(v[3]);
        }
        ((u16x4*)Wb)[j] = o;
    }
}

// ---------------------------------------------------------------------------
// Kernel 2: bf16 MFMA GEMM, double-buffered.  LT[n][m] = sum_c Xb[m][c]*Wb[n][c]
// 64x64 tile, BK=64, 4 waves (2x2, each 32x32), global_load_lds + XOR swizzle.
// Output written TRANSPOSED (n-major) so conv can read softmax rows coalesced.
// Grid 512 = 0 mod 8 -> simple bijective XCD swizzle (each XCD owns 8 m-panels).
// ---------------------------------------------------------------------------
__global__ __launch_bounds__(256) void gemm_mfma(const unsigned short* __restrict__ Xb,
                                                 const unsigned short* __restrict__ Wb,
                                                 float* __restrict__ LT) {
    __shared__ unsigned short As[2 * 64 * 64];   // 2 x 8 KB
    __shared__ unsigned short Bs[2 * 64 * 64];   // 2 x 8 KB

    const int tid = threadIdx.x;
    const int lane = tid & 63;
    const int wv = tid >> 6;
    const int wm = wv >> 1, wn = wv & 1;           // 2x2 wave grid

    int bid = blockIdx.x;
    bid = (bid & 7) * 64 + (bid >> 3);             // XCD-contiguous chunks
    const int n0 = (bid & 7) * 64;
    const int m0 = (bid >> 3) * 64;

    f32x4 acc[2][2] = {};

#define STAGE(ktt, bufsel) do {                                                  \
        const int k0s = (ktt) * 64;                                              \
        _Pragma("unroll")                                                        \
        for (int p = 0; p < 2; ++p) {                                            \
            const int c = p * 256 + tid;                                         \
            const int row = c >> 3, kcs = c & 7;                                 \
            const int kg = (kcs ^ (row & 7)) << 3;                               \
            gload_lds16(Xb + (size_t)(m0 + row) * CC + k0s + kg,                 \
                        (char*)As + (bufsel) * 8192 + c * 16);                   \
            gload_lds16(Wb + (size_t)(n0 + row) * CC + k0s + kg,                 \
                        (char*)Bs + (bufsel) * 8192 + c * 16);                   \
        }                                                                        \
    } while (0)

    int cur = 0;
    STAGE(0, 0);
    __syncthreads();

    for (int kt = 0; kt < CC / 64; ++kt) {
        if (kt + 1 < CC / 64) STAGE(kt + 1, cur ^ 1);   // prefetch next tile
        const char* Ab = (const char*)As + cur * 8192;
        const char* Bb = (const char*)Bs + cur * 8192;
#pragma unroll
        for (int ks = 0; ks < 2; ++ks) {
            short8 af[2], bfv[2];
            const int kc = ks * 4 + (lane >> 4);
#pragma unroll
            for (int s = 0; s < 2; ++s) {
                const int ra = wm * 32 + s * 16 + (lane & 15);
                af[s] = *(const short8*)(Ab + ra * 128 + ((kc ^ (ra & 7)) << 4));
                const int rb = wn * 32 + s * 16 + (lane & 15);
                bfv[s] = *(const short8*)(Bb + rb * 128 + ((kc ^ (rb & 7)) << 4));
            }
#pragma unroll
            for (int si = 0; si < 2; ++si)
#pragma unroll
                for (int sj = 0; sj < 2; ++sj)
                    acc[si][sj] = __builtin_amdgcn_mfma_f32_16x16x32_bf16(
                        af[si], bfv[sj], acc[si][sj], 0, 0, 0);
        }
        __syncthreads();   // drains vmcnt(0): prefetched tile is ready
        cur ^= 1;
    }
#undef STAGE

    // epilogue: C/D layout col=lane&15 (n), row=(lane>>4)*4+reg (m) [m89]
    // LT[n][m]: 4 consecutive m per lane -> f32x4 store
    const int col = lane & 15, rbase = (lane >> 4) * 4;
#pragma unroll
    for (int si = 0; si < 2; ++si)
#pragma unroll
        for (int sj = 0; sj < 2; ++sj) {
            const int n = n0 + wn * 32 + sj * 16 + col;
            if (n < NL) {
                const int m = m0 + wm * 32 + si * 16 + rbase;
                *(f32x4*)&LT[(size_t)n * MM + m] = acc[si][sj];
            }
        }
}

// ---------------------------------------------------------------------------
// Kernel 3: fused softmax + depthwise band conv.  Block = (b, h, 64-t tile).
// - logits staged k-major from LT (fully coalesced 256B rows)
// - softmax: 4 lanes per t, shfl_xor reduce, weights -> LDS [t][36] (f32x4-able)
// - x staged transposed, stride 100 + 16B-granule XOR swizzle (~2-way banks)
// - compute: weights = uniform LDS broadcasts, x = ds_read_b128, 8 t per lane
// ---------------------------------------------------------------------------
__global__ __launch_bounds__(256) void conv_fused(const float* __restrict__ X,
                                                  const float* __restrict__ LT,
                                                  float* __restrict__ out) {
    __shared__ float xsT[64 * 100];   // 25.6 KB
    __shared__ float lsm[32 * 64];    //  8 KB (k-major logits; row 31 unused)
    __shared__ float wsm[64 * 36];    //  9 KB (t-major weights, stride 36)

    const int tid = threadIdx.x, lane = tid & 63, wv = tid >> 6;
    int bid = blockIdx.x;
    const int tt = bid & 15;
    const int h = (bid >> 4) & 15;
    const int b = bid >> 8;
    const int t0 = tt * 64;

    // ---- stage x transposed (rows 94/95 zero; OOB t zero)
    for (int i = 0; i < 24; ++i) {
        const int row = i * 4 + wv;          // 0..95
        const int tg = t0 - PADL + row;
        float v = 0.f;
        if (row < 94 && tg >= 0 && tg < TT)
            v = X[(size_t)(b * TT + tg) * CC + h * RR + lane];
        const int tc = row >> 2;
        xsT[lane * 100 + ((tc ^ (lane & 7)) << 2) + (row & 3)] = v;
    }
    // ---- stage logits k-major: coalesced 256B per (wave,k)
#pragma unroll
    for (int i = 0; i < 8; ++i) {
        const int kk = wv * 8 + i;
        if (kk < KSZ)
            lsm[kk * 64 + lane] = LT[(size_t)(h * KSZ + kk) * MM + b * TT + t0 + lane];
    }
    __syncthreads();

    // ---- softmax: lanes (tl*4+j), j covers 8 k's, reduce via shfl_xor(1,2)
    {
        const int j = lane & 3, tl = wv * 16 + (lane >> 2);
        float v[8];
        float mx = -1e30f;
#pragma unroll
        for (int i = 0; i < 8; ++i) {
            const int kk = j * 8 + i;
            v[i] = (kk < KSZ) ? lsm[kk * 64 + tl] : -1e30f;
            mx = fmaxf(mx, v[i]);
        }
        mx = fmaxf(mx, __shfl_xor(mx, 1));
        mx = fmaxf(mx, __shfl_xor(mx, 2));
        float s = 0.f;
#pragma unroll
        for (int i = 0; i < 8; ++i) { v[i] = __expf(v[i] - mx); s += v[i]; }
        s += __shfl_xor(s, 1);
        s += __shfl_xor(s, 2);
        const float inv = 1.f / s;
#pragma unroll
        for (int i = 0; i < 8; ++i)
            wsm[tl * 36 + j * 8 + i] = v[i] * inv;   // k=31 -> exp(-inf)=0
    }
    __syncthreads();

    // ---- depthwise conv: 2 groups of 8 t per lane
#pragma unroll
    for (int g = 0; g < 2; ++g) {
        const int gl = wv * 16 + g * 8;
        f32x4 xw[10];
#pragma unroll
        for (int q = 0; q < 10; ++q) {
            const int tc = (gl >> 2) + q;
            xw[q] = *(const f32x4*)&xsT[lane * 100 + ((tc ^ (lane & 7)) << 2)];
        }
        float acc[8] = {};
#pragma unroll
        for (int tl8 = 0; tl8 < 8; ++tl8) {
            const float* wp = &wsm[(gl + tl8) * 36];
#pragma unroll
            for (int kq = 0; kq < 8; ++kq) {
                const f32x4 w4 = *(const f32x4*)(wp + kq * 4);  // uniform broadcast
#pragma unroll
                for (int jj = 0; jj < 4; ++jj) {
                    const int e = tl8 + kq * 4 + jj;            // static index
                    acc[tl8] = fmaf(w4[jj], xw[e >> 2][e & 3], acc[tl8]);
                }
            }
        }
#pragma unroll
        for (int tl8 = 0; tl8 < 8; ++tl8)
            out[(size_t)(b * TT + t0 + gl + tl8) * CC + h * RR + lane] = acc[tl8];
    }
}

// ---------------------------------------------------------------------------
extern "C" void kernel_launch(void* const* d_in, const int* in_sizes, int n_in,
                              void* d_out, int out_size, void* d_ws, size_t ws_size,
                              hipStream_t stream) {
    const float* x = (const float*)d_in[0];
    const float* W = (const float*)d_in[1];
    float* out = (float*)d_out;
    char* ws = (char*)d_ws;

    unsigned short* Xb = (unsigned short*)ws;                          // 8,388,608 B
    unsigned short* Wb = (unsigned short*)(ws + 8388608);              // 1,048,576 B
    float* LT = (float*)(ws + 9437184);                                // 8,126,464 B

    cast_kernel<<<(MM * CC / 4 + NP * CC / 4 + 255) / 256, 256, 0, stream>>>(x, W, Xb, Wb);
    gemm_mfma<<<NP / 64 * (MM / 64), 256, 0, stream>>>(Xb, Wb, LT);
    conv_fused<<<BB * HH * (TT / 64), 256, 0, stream>>>(x, LT, out);
}